// Round 3
// baseline (284.227 us; speedup 1.0000x reference)
//
#include <hip/hip_runtime.h>
#include <math.h>

#define HW4  12544                 // (224*224)/4
#define BATCH 128
#define NUM_CLASSES 1000
#define N4   (BATCH * HW4)         // 1,605,632 float4-groups
#define G    2                     // groups per thread
#define TPB  256
#define NTHREADS (N4 / G)          // 802,816
#define NBLOCKS  (NTHREADS / TPB)  // 3,136  (exact)

// ws layout (floats): ws[0] = pixel loss sum, ws[1] = class loss sum

__launch_bounds__(TPB, 4)   // allow up to ~128 VGPRs, 16 waves/CU
__global__ void pixel_loss_kernel(const float4* __restrict__ objects,
                                  const float4* __restrict__ locs,
                                  const float4* __restrict__ gt,
                                  const float* __restrict__ obj_coor_p,
                                  const float* __restrict__ no_obj_confi_p,
                                  float* __restrict__ ws) {
    const float coorW = *obj_coor_p;
    const float noW   = *no_obj_confi_p;

    const unsigned tid = blockIdx.x * TPB + threadIdx.x;

    // ---- phase 1: issue ALL 20 float4 loads (independent, stay in flight) ----
    float4 o[G], m4[G], gc[G][4], lc[G][4];
#pragma unroll
    for (int k = 0; k < G; ++k) {
        const unsigned g   = tid + (unsigned)(k * NTHREADS);
        const unsigned b   = g / HW4;             // magic-mul, cheap
        const unsigned hw4 = g - b * HW4;
        const unsigned gtb = b * (5 * HW4) + hw4;
        const unsigned lcb = b * (4 * HW4) + hw4;

        o[k]  = objects[g];
        m4[k] = gt[gtb];
#pragma unroll
        for (int c = 0; c < 4; ++c) {
            gc[k][c] = gt[gtb + (unsigned)((1 + c) * HW4)];
            lc[k][c] = locs[lcb + (unsigned)(c * HW4)];
        }
    }

    // Pin the schedule: nothing (especially the loads above) may be moved
    // across this point by the machine scheduler. Forces all 20 dwordx4
    // loads to be issued before the first consumer -> ~10KB in flight/wave.
    __builtin_amdgcn_sched_barrier(0);

    // ---- phase 2: branch-free compute ----
    float acc = 0.0f;
#pragma unroll
    for (int k = 0; k < G; ++k) {
        float4 sq = make_float4(0.f, 0.f, 0.f, 0.f);
#pragma unroll
        for (int c = 0; c < 4; ++c) {
            float dx = lc[k][c].x - gc[k][c].x;
            float dy = lc[k][c].y - gc[k][c].y;
            float dz = lc[k][c].z - gc[k][c].z;
            float dw = lc[k][c].w - gc[k][c].w;
            sq.x = fmaf(dx, dx, sq.x);
            sq.y = fmaf(dy, dy, sq.y);
            sq.z = fmaf(dz, dz, sq.z);
            sq.w = fmaf(dw, dw, sq.w);
        }
        const float* pv = (const float*)&o[k];
        const float* mv = (const float*)&m4[k];
        const float* sv = (const float*)&sq;
#pragma unroll
        for (int j = 0; j < 4; ++j) {
            const float p = pv[j];
            const float m = mv[j];           // exactly 0.0f or 1.0f
            const float lognop = fmaxf(__logf(1.0f - p), -100.0f);
            const float logp   = fmaxf(__logf(p), -100.0f);
            const float a = -noW * lognop;                 // m==0 contribution
            const float b = fmaf(coorW, sv[j], -logp);     // m==1 contribution
            acc += fmaf(m, b - a, a);                      // a + m*(b-a)
        }
    }

    // ---- wave (64-lane) reduce, then cross-wave via LDS ----
#pragma unroll
    for (int off = 32; off > 0; off >>= 1)
        acc += __shfl_down(acc, off, 64);

    __shared__ float smem[4];
    const int lane = threadIdx.x & 63;
    const int wave = threadIdx.x >> 6;
    if (lane == 0) smem[wave] = acc;
    __syncthreads();
    if (threadIdx.x == 0) {
        atomicAdd(&ws[0], smem[0] + smem[1] + smem[2] + smem[3]);
    }
}

__global__ void class_loss_kernel(const float* __restrict__ scores,
                                  const int* __restrict__ label,
                                  float* __restrict__ ws) {
    const int b = blockIdx.x;
    const float* row = scores + b * NUM_CLASSES;

    __shared__ float red[4];
    __shared__ float s_bcast;
    const int lane = threadIdx.x & 63;
    const int wave = threadIdx.x >> 6;

    // --- max reduce ---
    float mx = -INFINITY;
    for (int i = threadIdx.x; i < NUM_CLASSES; i += blockDim.x)
        mx = fmaxf(mx, row[i]);
#pragma unroll
    for (int off = 32; off > 0; off >>= 1)
        mx = fmaxf(mx, __shfl_down(mx, off, 64));
    if (lane == 0) red[wave] = mx;
    __syncthreads();
    if (threadIdx.x == 0)
        s_bcast = fmaxf(fmaxf(red[0], red[1]), fmaxf(red[2], red[3]));
    __syncthreads();
    mx = s_bcast;

    // --- sum(exp) reduce ---
    float se = 0.0f;
    for (int i = threadIdx.x; i < NUM_CLASSES; i += blockDim.x)
        se += __expf(row[i] - mx);
#pragma unroll
    for (int off = 32; off > 0; off >>= 1)
        se += __shfl_down(se, off, 64);
    __syncthreads();   // protect red[] reuse
    if (lane == 0) red[wave] = se;
    __syncthreads();
    if (threadIdx.x == 0) {
        float lse = mx + logf(red[0] + red[1] + red[2] + red[3]);
        atomicAdd(&ws[1], -(row[label[b]] - lse));
    }
}

__global__ void finalize_kernel(const float* __restrict__ ws,
                                const float* __restrict__ img_class_weight_p,
                                float* __restrict__ out) {
    if (threadIdx.x == 0 && blockIdx.x == 0) {
        float img_class_loss = ws[1] / (float)BATCH;
        out[0] = img_class_weight_p[0] * img_class_loss + ws[0] / (float)BATCH;
    }
}

extern "C" void kernel_launch(void* const* d_in, const int* in_sizes, int n_in,
                              void* d_out, int out_size, void* d_ws, size_t ws_size,
                              hipStream_t stream) {
    const float* objects = (const float*)d_in[0];   // (B,H,W)
    const float* scores  = (const float*)d_in[1];   // (B,1000)
    const float* locs    = (const float*)d_in[2];   // (B,4,H,W)
    const int*   label   = (const int*)d_in[3];     // (B,)
    const float* gt      = (const float*)d_in[4];   // (B,5,H,W)
    const float* obj_coor         = (const float*)d_in[5];
    const float* no_obj_confi     = (const float*)d_in[6];
    const float* img_class_weight = (const float*)d_in[7];

    float* ws  = (float*)d_ws;
    float* out = (float*)d_out;

    hipMemsetAsync(ws, 0, 2 * sizeof(float), stream);

    pixel_loss_kernel<<<NBLOCKS, TPB, 0, stream>>>(
        (const float4*)objects, (const float4*)locs, (const float4*)gt,
        obj_coor, no_obj_confi, ws);

    class_loss_kernel<<<BATCH, 256, 0, stream>>>(scores, label, ws);

    finalize_kernel<<<1, 64, 0, stream>>>(ws, img_class_weight, out);
}

// Round 4
// 282.330 us; speedup vs baseline: 1.0067x; 1.0067x over previous
//
#include <hip/hip_runtime.h>
#include <math.h>

#define HW4  12544                 // (224*224)/4
#define BATCH 128
#define NUM_CLASSES 1000
#define N4   (BATCH * HW4)         // 1,605,632 float4-groups
#define G    2                     // groups per thread
#define TPB  256
#define NTHREADS (N4 / G)          // 802,816
#define NBLOCKS  (NTHREADS / TPB)  // 3,136  (exact)

typedef float v4f __attribute__((ext_vector_type(4)));

// ws layout (floats): ws[0] = pixel loss sum, ws[1] = class loss sum

__launch_bounds__(TPB, 4)   // allow up to ~128 VGPRs, 16 waves/CU
__global__ void pixel_loss_kernel(const v4f* __restrict__ objects,
                                  const v4f* __restrict__ locs,
                                  const v4f* __restrict__ gt,
                                  const float* __restrict__ obj_coor_p,
                                  const float* __restrict__ no_obj_confi_p,
                                  float* __restrict__ ws) {
    const float coorW = *obj_coor_p;
    const float noW   = *no_obj_confi_p;

    const unsigned tid = blockIdx.x * TPB + threadIdx.x;

    // ---- phase 1: issue ALL 20 dwordx4 loads (independent, stay in flight) ----
    v4f o[G], m4[G], gc[G][4], lc[G][4];
#pragma unroll
    for (int k = 0; k < G; ++k) {
        const unsigned g   = tid + (unsigned)(k * NTHREADS);
        const unsigned b   = g / HW4;             // magic-mul, cheap
        const unsigned hw4 = g - b * HW4;
        const unsigned gtb = b * (5 * HW4) + hw4;
        const unsigned lcb = b * (4 * HW4) + hw4;

        o[k]  = objects[g];
        m4[k] = gt[gtb];
#pragma unroll
        for (int c = 0; c < 4; ++c) {
            gc[k][c] = gt[gtb + (unsigned)((1 + c) * HW4)];
            lc[k][c] = locs[lcb + (unsigned)(c * HW4)];
        }
    }

    // Hard data-dependency fence: one asm consuming ALL 20 load results as
    // register operands. The compiler cannot sink any load below this (each
    // result is an input), so all 20 must be issued before the single
    // s_waitcnt here -> ~10KB in flight per wave instead of ~2.5KB rounds.
    asm volatile(""
        : "+v"(o[0]),     "+v"(o[1]),
          "+v"(m4[0]),    "+v"(m4[1]),
          "+v"(gc[0][0]), "+v"(gc[0][1]), "+v"(gc[0][2]), "+v"(gc[0][3]),
          "+v"(gc[1][0]), "+v"(gc[1][1]), "+v"(gc[1][2]), "+v"(gc[1][3]),
          "+v"(lc[0][0]), "+v"(lc[0][1]), "+v"(lc[0][2]), "+v"(lc[0][3]),
          "+v"(lc[1][0]), "+v"(lc[1][1]), "+v"(lc[1][2]), "+v"(lc[1][3]));

    // ---- phase 2: branch-free compute ----
    float acc = 0.0f;
#pragma unroll
    for (int k = 0; k < G; ++k) {
        v4f sq = {0.f, 0.f, 0.f, 0.f};
#pragma unroll
        for (int c = 0; c < 4; ++c) {
            v4f d = lc[k][c] - gc[k][c];
            sq += d * d;
        }
#pragma unroll
        for (int j = 0; j < 4; ++j) {
            const float p = o[k][j];
            const float m = m4[k][j];        // exactly 0.0f or 1.0f
            const float lognop = fmaxf(__logf(1.0f - p), -100.0f);
            const float logp   = fmaxf(__logf(p), -100.0f);
            const float a = -noW * lognop;                 // m==0 contribution
            const float b = fmaf(coorW, sq[j], -logp);     // m==1 contribution
            acc += fmaf(m, b - a, a);                      // a + m*(b-a)
        }
    }

    // ---- wave (64-lane) reduce, then cross-wave via LDS ----
#pragma unroll
    for (int off = 32; off > 0; off >>= 1)
        acc += __shfl_down(acc, off, 64);

    __shared__ float smem[4];
    const int lane = threadIdx.x & 63;
    const int wave = threadIdx.x >> 6;
    if (lane == 0) smem[wave] = acc;
    __syncthreads();
    if (threadIdx.x == 0) {
        atomicAdd(&ws[0], smem[0] + smem[1] + smem[2] + smem[3]);
    }
}

__global__ void class_loss_kernel(const float* __restrict__ scores,
                                  const int* __restrict__ label,
                                  float* __restrict__ ws) {
    const int b = blockIdx.x;
    const float* row = scores + b * NUM_CLASSES;

    __shared__ float red[4];
    __shared__ float s_bcast;
    const int lane = threadIdx.x & 63;
    const int wave = threadIdx.x >> 6;

    // --- max reduce ---
    float mx = -INFINITY;
    for (int i = threadIdx.x; i < NUM_CLASSES; i += blockDim.x)
        mx = fmaxf(mx, row[i]);
#pragma unroll
    for (int off = 32; off > 0; off >>= 1)
        mx = fmaxf(mx, __shfl_down(mx, off, 64));
    if (lane == 0) red[wave] = mx;
    __syncthreads();
    if (threadIdx.x == 0)
        s_bcast = fmaxf(fmaxf(red[0], red[1]), fmaxf(red[2], red[3]));
    __syncthreads();
    mx = s_bcast;

    // --- sum(exp) reduce ---
    float se = 0.0f;
    for (int i = threadIdx.x; i < NUM_CLASSES; i += blockDim.x)
        se += __expf(row[i] - mx);
#pragma unroll
    for (int off = 32; off > 0; off >>= 1)
        se += __shfl_down(se, off, 64);
    __syncthreads();   // protect red[] reuse
    if (lane == 0) red[wave] = se;
    __syncthreads();
    if (threadIdx.x == 0) {
        float lse = mx + logf(red[0] + red[1] + red[2] + red[3]);
        atomicAdd(&ws[1], -(row[label[b]] - lse));
    }
}

__global__ void finalize_kernel(const float* __restrict__ ws,
                                const float* __restrict__ img_class_weight_p,
                                float* __restrict__ out) {
    if (threadIdx.x == 0 && blockIdx.x == 0) {
        float img_class_loss = ws[1] / (float)BATCH;
        out[0] = img_class_weight_p[0] * img_class_loss + ws[0] / (float)BATCH;
    }
}

extern "C" void kernel_launch(void* const* d_in, const int* in_sizes, int n_in,
                              void* d_out, int out_size, void* d_ws, size_t ws_size,
                              hipStream_t stream) {
    const float* objects = (const float*)d_in[0];   // (B,H,W)
    const float* scores  = (const float*)d_in[1];   // (B,1000)
    const float* locs    = (const float*)d_in[2];   // (B,4,H,W)
    const int*   label   = (const int*)d_in[3];     // (B,)
    const float* gt      = (const float*)d_in[4];   // (B,5,H,W)
    const float* obj_coor         = (const float*)d_in[5];
    const float* no_obj_confi     = (const float*)d_in[6];
    const float* img_class_weight = (const float*)d_in[7];

    float* ws  = (float*)d_ws;
    float* out = (float*)d_out;

    hipMemsetAsync(ws, 0, 2 * sizeof(float), stream);

    pixel_loss_kernel<<<NBLOCKS, TPB, 0, stream>>>(
        (const v4f*)objects, (const v4f*)locs, (const v4f*)gt,
        obj_coor, no_obj_confi, ws);

    class_loss_kernel<<<BATCH, 256, 0, stream>>>(scores, label, ws);

    finalize_kernel<<<1, 64, 0, stream>>>(ws, img_class_weight, out);
}